// Round 7
// baseline (1157.675 us; speedup 1.0000x reference)
//
#include <hip/hip_runtime.h>
#include <hip/hip_bf16.h>

// Problem constants
#define S_LEN 2048
#define BB 32
#define EE 300
#define HH 256
#define VV 50000
#define GG 5

// 2*log2(e): folded into W_ih/W_hh/biases at pack time so tanh needs no input scaling
#define K2LOG2E 2.8853900817779268f

typedef float f32x4 __attribute__((ext_vector_type(4)));
typedef float f32x2 __attribute__((ext_vector_type(2)));
typedef __bf16 bf16x8 __attribute__((ext_vector_type(8)));
typedef int i32x4 __attribute__((ext_vector_type(4)));

// ---------- helpers ----------
__device__ __forceinline__ unsigned short f2bf(float f) {
    unsigned int u = __builtin_bit_cast(unsigned int, f);
    u = u + 0x7fffu + ((u >> 16) & 1u);   // RNE
    return (unsigned short)(u >> 16);
}
__device__ __forceinline__ float bflo(unsigned int w) {
    return __builtin_bit_cast(float, w << 16);
}
__device__ __forceinline__ float bfhi(unsigned int w) {
    return __builtin_bit_cast(float, w & 0xffff0000u);
}
// tanh for PRE-SCALED input (x already multiplied by 2*log2(e)): 2 VALU + 2 trans
__device__ __forceinline__ float tanh_pre(float xs) {
    float e = __builtin_amdgcn_exp2f(xs);
    float r = __builtin_amdgcn_rcpf(e + 1.0f);
    return __builtin_fmaf(-2.0f, r, 1.0f);
}
// tanh for unscaled input (head kernel only)
__device__ __forceinline__ float tanhf_fast(float x) {
    return tanh_pre(x * K2LOG2E);
}
// pack two f32 -> dword of 2 bf16 (RNE), single instruction
__device__ __forceinline__ unsigned int cvt_pk_bf16(float lo, float hi) {
    unsigned int r;
    asm("v_cvt_pk_bf16_f32 %0, %1, %2" : "=v"(r) : "v"(lo), "v"(hi));
    return r;
}
// packed f32 add (VOP3P), one instruction for two sums
__device__ __forceinline__ f32x2 pk_add(f32x2 a, f32x2 b) {
    f32x2 d;
    asm("v_pk_add_f32 %0, %1, %2" : "=v"(d) : "v"(a), "v"(b));
    return d;
}

// ---------- K0: pack weights into MFMA-fragment-friendly bf16 layouts ----------
// All recurrence-path weights/biases are pre-scaled by 2*log2(e).
// Wp  [dir][kb(10)][kg(4)][j(256)][i(8)]  <- K2*W_ih[j][e], e = kb*32+kg*8+i (zero-pad e>=300)
// Whp [dir][kb(8) ][kg(4)][j(256)][i(8)]  <- K2*W_hh[j][k], k = kb*32+kg*8+i
// biasc[dir*256+j] = K2*(b_ih[j] + b_hh[j])
__global__ void k_pack(const float* __restrict__ Wih_f, const float* __restrict__ Whh_f,
                       const float* __restrict__ bih_f, const float* __restrict__ bhh_f,
                       const float* __restrict__ Wih_b, const float* __restrict__ Whh_b,
                       const float* __restrict__ bih_b, const float* __restrict__ bhh_b,
                       unsigned short* __restrict__ Wp, unsigned short* __restrict__ Whp,
                       float* __restrict__ biasc)
{
    int idx = blockIdx.x * 256 + threadIdx.x;
    if (idx < 163840) {
        int i = idx & 7, j = (idx >> 3) & 255, kg = (idx >> 11) & 3, kbd = idx >> 13;
        int kb = kbd % 10, dir = kbd / 10;
        int e = kb * 32 + kg * 8 + i;
        const float* W = dir ? Wih_b : Wih_f;
        float v = (e < EE) ? W[j * EE + e] * K2LOG2E : 0.0f;
        Wp[idx] = f2bf(v);
    } else if (idx < 163840 + 131072) {
        int x = idx - 163840;
        int i = x & 7, j = (x >> 3) & 255, kg = (x >> 11) & 3, kbd = x >> 13;
        int kb = kbd & 7, dir = kbd >> 3;
        int k = kb * 32 + kg * 8 + i;
        const float* W = dir ? Whh_b : Whh_f;
        Whp[x] = f2bf(W[j * HH + k] * K2LOG2E);
    } else if (idx < 163840 + 131072 + 512) {
        int x = idx - (163840 + 131072);
        int j = x & 255, dir = x >> 8;
        biasc[x] = (dir ? (bih_b[j] + bhh_b[j]) : (bih_f[j] + bhh_f[j])) * K2LOG2E;
    }
}

// ---------- K2: embedding gather + input projection (transposed MFMA GEMM) ----------
// xq[s][dir][half][w4][lane][16 bf16]: [t(4)][r(4)] =
//   K2 * (xproj^T(j = w4*64+t*16+(lane>>4)*4+r , b = half*16+(lane&15)) + bias[j])
__global__ __launch_bounds__(1024) void k_xproj(
    const int* __restrict__ tok, const float* __restrict__ emb,
    const unsigned short* __restrict__ Wp, const float* __restrict__ biasc,
    unsigned short* __restrict__ xq)
{
    __shared__ char xs[32 * 640];   // x[b][e(320)] bf16, XOR-swizzled rows
    int s = blockIdx.x;
    int tid = threadIdx.x;
    int lane = tid & 63, W16 = tid >> 6;

    #pragma unroll
    for (int k = 0; k < 5; k++) ((int*)xs)[tid + k * 1024] = 0;
    __syncthreads();

    {
        int b0 = W16 * 2;
        for (int rr = 0; rr < 2; rr++) {
            int b = b0 + rr;
            int t = tok[b * S_LEN + s];
            const float* row = emb + (size_t)t * EE;
            int xorv = (b & 7) << 4;
            #pragma unroll
            for (int c = 0; c < 5; c++) {
                int e = c * 64 + lane;
                if (e < EE) {
                    *(unsigned short*)(xs + b * 640 + ((2 * e) ^ xorv)) = f2bf(row[e]);
                }
            }
        }
    }
    __syncthreads();

    int dir = W16 >> 3, w = (W16 >> 1) & 3, half = W16 & 1;
    int l15 = lane & 15, kg = lane >> 4;
    f32x4 acc[4] = {};
    int brow = half * 16 + l15;
    int bxor = (brow & 7) << 4;
    const char* xrow = xs + brow * 640;

    #pragma unroll
    for (int kb = 0; kb < 10; kb++) {
        bf16x8 xb = *(const bf16x8*)(xrow + ((kb * 64 + kg * 16) ^ bxor));
        #pragma unroll
        for (int t = 0; t < 4; t++) {
            int j = w * 64 + t * 16 + l15;
            bf16x8 wa = *(const bf16x8*)(Wp + (size_t)(((dir * 10 + kb) * 4 + kg) * 256 + j) * 8);
            acc[t] = __builtin_amdgcn_mfma_f32_16x16x32_bf16(wa, xb, acc[t], 0, 0, 0);
        }
    }

    unsigned int words[8];
    #pragma unroll
    for (int t = 0; t < 4; t++) {
        float v[4];
        #pragma unroll
        for (int r = 0; r < 4; r++) {
            int j = w * 64 + t * 16 + kg * 4 + r;
            v[r] = acc[t][r] + biasc[dir * 256 + j];
        }
        words[t * 2 + 0] = cvt_pk_bf16(v[0], v[1]);
        words[t * 2 + 1] = cvt_pk_bf16(v[2], v[3]);
    }
    size_t base = (size_t)s * 32768 + (size_t)((dir * 2 + half) * 4 + w) * 2048 + (size_t)lane * 32;
    *(i32x4*)((char*)xq + base) = *(i32x4*)&words[0];
    *(i32x4*)((char*)xq + base + 16) = *(i32x4*)&words[4];
}

// ---------- K3: the sequential recurrence (4 persistent workgroups, 8 waves each) ----------
// block = (dir, batch-half). 8 waves -> 2 waves/SIMD. Wave w owns j in [w*32, w*32+32)
// as TWO MFMA chains (quads q=0,1) sharing each ds_read h-fragment -> LDS read traffic
// halves to 64KB/step/CU (was 128KB = the R6 wall). W_hh (pre-scaled) resident in VGPRs.
// h in LDS, k-blocked [kb(8)][kg(4)][b(16)][i(8)] bf16 (conflict-free by construction).
// xproj unpacked directly into the MFMA C-init; xq prefetched 2 steps ahead; raw
// lgkm-only barrier keeps the global prefetch in flight.
__global__ __launch_bounds__(512, 2) void k_rnn(
    const unsigned short* __restrict__ xq,
    const unsigned short* __restrict__ Whp,
    float* __restrict__ pooled)
{
    __shared__ char hb0[8192];
    __shared__ char hb1[8192];
    int bid = blockIdx.x;
    int dir = bid >> 1, half = bid & 1;
    int tid = threadIdx.x;
    int lane = tid & 63, w = tid >> 6;          // w in 0..7
    int l15 = lane & 15, kg = lane >> 4;

    // resident W_hh fragments: quad q, lane holds W[j = w*32+q*16+l15][k = kb*32+kg*8 ..+8]
    bf16x8 wf0[8], wf1[8];
    #pragma unroll
    for (int kb = 0; kb < 8; kb++) {
        int jbase = (((dir * 8 + kb) * 4 + kg) * 256 + w * 32 + l15);
        wf0[kb] = *(const bf16x8*)(Whp + (size_t)jbase * 8);
        wf1[kb] = *(const bf16x8*)(Whp + (size_t)(jbase + 16) * 8);
    }

    // zero h buffer 0 (h_0 = 0): 512 threads x 16B = 8192B
    *(i32x4*)(&hb0[tid * 16]) = i32x4{0, 0, 0, 0};

    f32x2 px[4] = {};   // pool pairs: [q*2 + rpair]

    // read cells: h[b=l15][k=kb*1024.. ] at kb*1024 + kg*256 + l15*16
    int rbase = kg * 256 + l15 * 16;
    // write cell quad q: j=w*32+q*16+kg*4+r -> w*1024 + (q*2+(kg>>1))*256 + l15*16 + (kg&1)*8
    int woff0 = w * 1024 + (kg >> 1) * 256 + l15 * 16 + (kg & 1) * 8;
    int woff1 = woff0 + 512;

    // xq record: 32B per (w4=w>>1, lane); wave w reads the 16B half (w&1) = its two quads
    int lanebase = ((dir * 2 + half) * 4 + (w >> 1)) * 2048 + lane * 32 + (w & 1) * 16;
    int sdelta = dir ? -32768 : 32768;
    int s0 = dir ? (S_LEN - 1) : 0;

    const char* xqb = (const char*)xq;   // uniform base (SGPR) + 32-bit lane offset
    int xoff = s0 * 32768 + lanebase;
    i32x4 xc0 = *(const i32x4*)(xqb + xoff); xoff += sdelta;   // step 0
    i32x4 xc1 = *(const i32x4*)(xqb + xoff); xoff += sdelta;   // step 1; xoff -> step 2

    __syncthreads();

#define STEP(RB, WB, XC, DO_PF)                                                      \
    {                                                                                \
        const char* rb = (RB) + rbase;                                               \
        bf16x8 hf[8];                                                                \
        _Pragma("unroll")                                                            \
        for (int kb = 0; kb < 8; kb++)                                               \
            hf[kb] = *(const bf16x8*)(rb + kb * 1024);                               \
        f32x4 acc0, acc1;                                                            \
        acc0[0] = bflo((unsigned int)XC[0]);                                         \
        acc0[1] = bfhi((unsigned int)XC[0]);                                         \
        acc0[2] = bflo((unsigned int)XC[1]);                                         \
        acc0[3] = bfhi((unsigned int)XC[1]);                                         \
        acc1[0] = bflo((unsigned int)XC[2]);                                         \
        acc1[1] = bfhi((unsigned int)XC[2]);                                         \
        acc1[2] = bflo((unsigned int)XC[3]);                                         \
        acc1[3] = bfhi((unsigned int)XC[3]);                                         \
        if (DO_PF) { XC = *(const i32x4*)(xqb + xoff); xoff += sdelta; }             \
        _Pragma("unroll")                                                            \
        for (int kb = 0; kb < 8; kb++) {                                             \
            acc0 = __builtin_amdgcn_mfma_f32_16x16x32_bf16(wf0[kb], hf[kb],          \
                                                           acc0, 0, 0, 0);           \
            acc1 = __builtin_amdgcn_mfma_f32_16x16x32_bf16(wf1[kb], hf[kb],          \
                                                           acc1, 0, 0, 0);           \
        }                                                                            \
        float h0 = tanh_pre(acc0[0]);                                                \
        float h1 = tanh_pre(acc0[1]);                                                \
        float h2 = tanh_pre(acc0[2]);                                                \
        float h3 = tanh_pre(acc0[3]);                                                \
        float h4 = tanh_pre(acc1[0]);                                                \
        float h5 = tanh_pre(acc1[1]);                                                \
        float h6 = tanh_pre(acc1[2]);                                                \
        float h7 = tanh_pre(acc1[3]);                                                \
        *(uint2*)((WB) + woff0) = make_uint2(cvt_pk_bf16(h0, h1),                    \
                                             cvt_pk_bf16(h2, h3));                   \
        *(uint2*)((WB) + woff1) = make_uint2(cvt_pk_bf16(h4, h5),                    \
                                             cvt_pk_bf16(h6, h7));                   \
        asm volatile("s_waitcnt lgkmcnt(0)" ::: "memory");                           \
        __builtin_amdgcn_s_barrier();                                                \
        px[0] = pk_add(px[0], f32x2{h0, h1});                                        \
        px[1] = pk_add(px[1], f32x2{h2, h3});                                        \
        px[2] = pk_add(px[2], f32x2{h4, h5});                                        \
        px[3] = pk_add(px[3], f32x2{h6, h7});                                        \
    }

    // steps 0 .. S_LEN-5 (prefetch target i+2 always valid)
    for (int i = 0; i < S_LEN - 4; i += 2) {
        STEP(hb0, hb1, xc0, 1)
        STEP(hb1, hb0, xc1, 1)
    }
    // steps S_LEN-4 .. S_LEN-1
    STEP(hb0, hb1, xc0, 1)   // prefetches S_LEN-2
    STEP(hb1, hb0, xc1, 1)   // prefetches S_LEN-1
    STEP(hb0, hb1, xc0, 0)
    STEP(hb1, hb0, xc1, 0)
#undef STEP

    // write pooled sums (mean division happens in k_head)
    #pragma unroll
    for (int q = 0; q < 2; q++)
        #pragma unroll
        for (int r = 0; r < 4; r++) {
            int j = w * 32 + q * 16 + kg * 4 + r;
            int b = half * 16 + l15;
            pooled[b * 512 + dir * 256 + j] = px[q * 2 + (r >> 1)][r & 1];
        }
}

// ---------- K4: head: tanh(mean) @ fc_W^T + fc_b ----------
__global__ __launch_bounds__(64) void k_head(
    const float* __restrict__ pooled, const float* __restrict__ fcW,
    const float* __restrict__ fcb, float* __restrict__ out)
{
    int b = blockIdx.x;
    int lane = threadIdx.x;
    float p[GG] = {0, 0, 0, 0, 0};
    for (int jj = lane; jj < 512; jj += 64) {
        float a = tanhf_fast(pooled[b * 512 + jj] * (1.0f / 2048.0f));
        #pragma unroll
        for (int g = 0; g < GG; g++) p[g] += a * fcW[g * 512 + jj];
    }
    #pragma unroll
    for (int g = 0; g < GG; g++)
        #pragma unroll
        for (int off = 32; off; off >>= 1) p[g] += __shfl_xor(p[g], off);
    if (lane == 0) {
        #pragma unroll
        for (int g = 0; g < GG; g++) out[b * GG + g] = p[g] + fcb[g];
    }
}

// ---------- launcher ----------
extern "C" void kernel_launch(void* const* d_in, const int* in_sizes, int n_in,
                              void* d_out, int out_size, void* d_ws, size_t ws_size,
                              hipStream_t stream)
{
    const int* tok = (const int*)d_in[0];
    const float* emb = (const float*)d_in[1];
    const float* Wih_f = (const float*)d_in[2];
    const float* Whh_f = (const float*)d_in[3];
    const float* bih_f = (const float*)d_in[4];
    const float* bhh_f = (const float*)d_in[5];
    const float* Wih_b = (const float*)d_in[6];
    const float* Whh_b = (const float*)d_in[7];
    const float* bih_b = (const float*)d_in[8];
    const float* bhh_b = (const float*)d_in[9];
    const float* fcW = (const float*)d_in[10];
    const float* fcb = (const float*)d_in[11];
    float* out = (float*)d_out;

    char* ws = (char*)d_ws;
    unsigned short* xq   = (unsigned short*)(ws);                       // 67,108,864 B
    unsigned short* Wp   = (unsigned short*)(ws + 67108864);            //    327,680 B
    unsigned short* Whp  = (unsigned short*)(ws + 67108864 + 327680);   //    262,144 B
    float* biasc         = (float*)(ws + 67108864 + 327680 + 262144);   //      2,048 B
    float* pooled        = (float*)(ws + 67108864 + 327680 + 262144 + 2048); // 65,536 B

    hipLaunchKernelGGL(k_pack, dim3(1154), dim3(256), 0, stream,
                       Wih_f, Whh_f, bih_f, bhh_f, Wih_b, Whh_b, bih_b, bhh_b,
                       Wp, Whp, biasc);
    hipLaunchKernelGGL(k_xproj, dim3(2048), dim3(1024), 0, stream,
                       tok, emb, Wp, biasc, xq);
    hipLaunchKernelGGL(k_rnn, dim3(4), dim3(512), 0, stream, xq, Whp, pooled);
    hipLaunchKernelGGL(k_head, dim3(32), dim3(64), 0, stream, pooled, fcW, fcb, out);
}

// Round 8
// 1091.000 us; speedup vs baseline: 1.0611x; 1.0611x over previous
//
#include <hip/hip_runtime.h>
#include <hip/hip_bf16.h>

// Problem constants
#define S_LEN 2048
#define BB 32
#define EE 300
#define HH 256
#define VV 50000
#define GG 5

// 2*log2(e): folded into W_ih/W_hh/biases at pack time so tanh needs no input scaling
#define K2LOG2E 2.8853900817779268f

typedef float f32x4 __attribute__((ext_vector_type(4)));
typedef float f32x2 __attribute__((ext_vector_type(2)));
typedef __bf16 bf16x8 __attribute__((ext_vector_type(8)));
typedef int i32x4 __attribute__((ext_vector_type(4)));

// ---------- helpers ----------
__device__ __forceinline__ unsigned short f2bf(float f) {
    unsigned int u = __builtin_bit_cast(unsigned int, f);
    u = u + 0x7fffu + ((u >> 16) & 1u);   // RNE
    return (unsigned short)(u >> 16);
}
__device__ __forceinline__ float bflo(unsigned int w) {
    return __builtin_bit_cast(float, w << 16);
}
__device__ __forceinline__ float bfhi(unsigned int w) {
    return __builtin_bit_cast(float, w & 0xffff0000u);
}
// tanh for PRE-SCALED input (x already multiplied by 2*log2(e)): 2 VALU + 2 trans
__device__ __forceinline__ float tanh_pre(float xs) {
    float e = __builtin_amdgcn_exp2f(xs);
    float r = __builtin_amdgcn_rcpf(e + 1.0f);
    return __builtin_fmaf(-2.0f, r, 1.0f);
}
// tanh for unscaled input (head kernel only)
__device__ __forceinline__ float tanhf_fast(float x) {
    return tanh_pre(x * K2LOG2E);
}
// pack two f32 -> dword of 2 bf16 (RNE), single instruction
__device__ __forceinline__ unsigned int cvt_pk_bf16(float lo, float hi) {
    unsigned int r;
    asm("v_cvt_pk_bf16_f32 %0, %1, %2" : "=v"(r) : "v"(lo), "v"(hi));
    return r;
}
// packed f32 add (VOP3P), one instruction for two sums
__device__ __forceinline__ f32x2 pk_add(f32x2 a, f32x2 b) {
    f32x2 d;
    asm("v_pk_add_f32 %0, %1, %2" : "=v"(d) : "v"(a), "v"(b));
    return d;
}

// ---------- K0: pack weights into MFMA-fragment-friendly bf16 layouts ----------
// All recurrence-path weights/biases are pre-scaled by 2*log2(e).
// Wp  [dir][kb(10)][kg(4)][j(256)][i(8)]  <- K2*W_ih[j][e], e = kb*32+kg*8+i (zero-pad e>=300)
// Whp [dir][kb(8) ][kg(4)][j(256)][i(8)]  <- K2*W_hh[j][k], k = kb*32+kg*8+i
// biasc[dir*256+j] = K2*(b_ih[j] + b_hh[j])
__global__ void k_pack(const float* __restrict__ Wih_f, const float* __restrict__ Whh_f,
                       const float* __restrict__ bih_f, const float* __restrict__ bhh_f,
                       const float* __restrict__ Wih_b, const float* __restrict__ Whh_b,
                       const float* __restrict__ bih_b, const float* __restrict__ bhh_b,
                       unsigned short* __restrict__ Wp, unsigned short* __restrict__ Whp,
                       float* __restrict__ biasc)
{
    int idx = blockIdx.x * 256 + threadIdx.x;
    if (idx < 163840) {
        int i = idx & 7, j = (idx >> 3) & 255, kg = (idx >> 11) & 3, kbd = idx >> 13;
        int kb = kbd % 10, dir = kbd / 10;
        int e = kb * 32 + kg * 8 + i;
        const float* W = dir ? Wih_b : Wih_f;
        float v = (e < EE) ? W[j * EE + e] * K2LOG2E : 0.0f;
        Wp[idx] = f2bf(v);
    } else if (idx < 163840 + 131072) {
        int x = idx - 163840;
        int i = x & 7, j = (x >> 3) & 255, kg = (x >> 11) & 3, kbd = x >> 13;
        int kb = kbd & 7, dir = kbd >> 3;
        int k = kb * 32 + kg * 8 + i;
        const float* W = dir ? Whh_b : Whh_f;
        Whp[x] = f2bf(W[j * HH + k] * K2LOG2E);
    } else if (idx < 163840 + 131072 + 512) {
        int x = idx - (163840 + 131072);
        int j = x & 255, dir = x >> 8;
        biasc[x] = (dir ? (bih_b[j] + bhh_b[j]) : (bih_f[j] + bhh_f[j])) * K2LOG2E;
    }
}

// ---------- K2: embedding gather + input projection (transposed MFMA GEMM) ----------
// xq[s][dir][half][w4][lane][16 bf16]: [t(4)][r(4)] =
//   K2 * (xproj^T(j = w4*64+t*16+(lane>>4)*4+r , b = half*16+(lane&15)) + bias[j])
__global__ __launch_bounds__(1024) void k_xproj(
    const int* __restrict__ tok, const float* __restrict__ emb,
    const unsigned short* __restrict__ Wp, const float* __restrict__ biasc,
    unsigned short* __restrict__ xq)
{
    __shared__ char xs[32 * 640];   // x[b][e(320)] bf16, XOR-swizzled rows
    int s = blockIdx.x;
    int tid = threadIdx.x;
    int lane = tid & 63, W16 = tid >> 6;

    #pragma unroll
    for (int k = 0; k < 5; k++) ((int*)xs)[tid + k * 1024] = 0;
    __syncthreads();

    {
        int b0 = W16 * 2;
        for (int rr = 0; rr < 2; rr++) {
            int b = b0 + rr;
            int t = tok[b * S_LEN + s];
            const float* row = emb + (size_t)t * EE;
            int xorv = (b & 7) << 4;
            #pragma unroll
            for (int c = 0; c < 5; c++) {
                int e = c * 64 + lane;
                if (e < EE) {
                    *(unsigned short*)(xs + b * 640 + ((2 * e) ^ xorv)) = f2bf(row[e]);
                }
            }
        }
    }
    __syncthreads();

    int dir = W16 >> 3, w = (W16 >> 1) & 3, half = W16 & 1;
    int l15 = lane & 15, kg = lane >> 4;
    f32x4 acc[4] = {};
    int brow = half * 16 + l15;
    int bxor = (brow & 7) << 4;
    const char* xrow = xs + brow * 640;

    #pragma unroll
    for (int kb = 0; kb < 10; kb++) {
        bf16x8 xb = *(const bf16x8*)(xrow + ((kb * 64 + kg * 16) ^ bxor));
        #pragma unroll
        for (int t = 0; t < 4; t++) {
            int j = w * 64 + t * 16 + l15;
            bf16x8 wa = *(const bf16x8*)(Wp + (size_t)(((dir * 10 + kb) * 4 + kg) * 256 + j) * 8);
            acc[t] = __builtin_amdgcn_mfma_f32_16x16x32_bf16(wa, xb, acc[t], 0, 0, 0);
        }
    }

    unsigned int words[8];
    #pragma unroll
    for (int t = 0; t < 4; t++) {
        float v[4];
        #pragma unroll
        for (int r = 0; r < 4; r++) {
            int j = w * 64 + t * 16 + kg * 4 + r;
            v[r] = acc[t][r] + biasc[dir * 256 + j];
        }
        words[t * 2 + 0] = cvt_pk_bf16(v[0], v[1]);
        words[t * 2 + 1] = cvt_pk_bf16(v[2], v[3]);
    }
    size_t base = (size_t)s * 32768 + (size_t)((dir * 2 + half) * 4 + w) * 2048 + (size_t)lane * 32;
    *(i32x4*)((char*)xq + base) = *(i32x4*)&words[0];
    *(i32x4*)((char*)xq + base + 16) = *(i32x4*)&words[4];
}

// ---------- K3: the sequential recurrence (4 persistent workgroups, 12 waves each) ----------
// block = (dir, batch-half). 12 waves -> 3 waves/SIMD (TLP) with only 96KB/step LDS reads
// (vs 128KB at 16 waves = the R6 wall). 16 j-tiles of 16 cols; tile group g=w/3 owns
// tiles {4g..4g+3}: wave w%3==0 computes tiles 4g,4g+1 (two interleaved chains, reads h
// ONCE for both), w%3==1 -> tile 4g+2, w%3==2 -> tile 4g+3. MFMA stays 32/SIMD/step
// under both round-robin and blocked wave->SIMD mappings. Double-chain waves (per-step
// stragglers) run at s_setprio(1). h in LDS, k-blocked [kb(8)][kg(4)][b(16)][i(8)] bf16
// (conflict-free). xproj as MFMA C-init; 2-step-ahead prefetch; raw lgkm-only barrier.
__global__ __launch_bounds__(768, 3) void k_rnn(
    const unsigned short* __restrict__ xq,
    const unsigned short* __restrict__ Whp,
    float* __restrict__ pooled)
{
    __shared__ char hb0[8192];
    __shared__ char hb1[8192];
    int bid = blockIdx.x;
    int dir = bid >> 1, half = bid & 1;
    int tid = threadIdx.x;
    int lane = tid & 63, w = tid >> 6;          // w in 0..11
    int l15 = lane & 15, kg = lane >> 4;
    int g = w / 3, r = w % 3;                   // tile group, role

    // zero h buffer 0 (h_0 = 0)
    if (tid < 512) *(i32x4*)(&hb0[tid * 16]) = i32x4{0, 0, 0, 0};

    // read cells: h[b=l15][k=kb*32+kg*8 ..+8] at kb*1024 + kg*256 + l15*16
    int rbase = kg * 256 + l15 * 16;
#define WOFF(t) (((t) >> 1) * 1024 + (((t) & 1) * 2 + (kg >> 1)) * 256 + l15 * 16 + (kg & 1) * 8)

    int sdelta = dir ? -32768 : 32768;
    int s0 = dir ? (S_LEN - 1) : 0;
    const char* xqb = (const char*)xq;   // uniform base (SGPR) + 32-bit offset
    int xrec = ((dir * 2 + half) * 4 + g) * 2048 + lane * 32;

    __syncthreads();

    if (r == 0) {
        // ---- double-chain wave: tiles t0 = 4g, t1 = 4g+1 ----
        int t0 = 4 * g, t1 = 4 * g + 1;
        bf16x8 wf0[8], wf1[8];
        #pragma unroll
        for (int kb = 0; kb < 8; kb++) {
            int jb = ((dir * 8 + kb) * 4 + kg) * 256;
            wf0[kb] = *(const bf16x8*)(Whp + (size_t)(jb + t0 * 16 + l15) * 8);
            wf1[kb] = *(const bf16x8*)(Whp + (size_t)(jb + t1 * 16 + l15) * 8);
        }
        int woff0 = WOFF(t0), woff1 = WOFF(t1);
        int xoff = s0 * 32768 + xrec;            // quarters 0,1 (16B)
        i32x4 xc0 = *(const i32x4*)(xqb + xoff); xoff += sdelta;
        i32x4 xc1 = *(const i32x4*)(xqb + xoff); xoff += sdelta;
        f32x2 px[4] = {};
        __builtin_amdgcn_s_setprio(1);

#define STEP2(RB, WB, XC, DO_PF)                                                     \
    {                                                                                \
        const char* rb = (RB) + rbase;                                               \
        bf16x8 hf[8];                                                                \
        _Pragma("unroll")                                                            \
        for (int kb = 0; kb < 8; kb++)                                               \
            hf[kb] = *(const bf16x8*)(rb + kb * 1024);                               \
        f32x4 acc0, acc1;                                                            \
        acc0[0] = bflo((unsigned int)XC[0]);                                         \
        acc0[1] = bfhi((unsigned int)XC[0]);                                         \
        acc0[2] = bflo((unsigned int)XC[1]);                                         \
        acc0[3] = bfhi((unsigned int)XC[1]);                                         \
        acc1[0] = bflo((unsigned int)XC[2]);                                         \
        acc1[1] = bfhi((unsigned int)XC[2]);                                         \
        acc1[2] = bflo((unsigned int)XC[3]);                                         \
        acc1[3] = bfhi((unsigned int)XC[3]);                                         \
        if (DO_PF) { XC = *(const i32x4*)(xqb + xoff); xoff += sdelta; }             \
        _Pragma("unroll")                                                            \
        for (int kb = 0; kb < 8; kb++) {                                             \
            acc0 = __builtin_amdgcn_mfma_f32_16x16x32_bf16(wf0[kb], hf[kb],          \
                                                           acc0, 0, 0, 0);           \
            acc1 = __builtin_amdgcn_mfma_f32_16x16x32_bf16(wf1[kb], hf[kb],          \
                                                           acc1, 0, 0, 0);           \
        }                                                                            \
        float h0 = tanh_pre(acc0[0]);                                                \
        float h1 = tanh_pre(acc0[1]);                                                \
        float h2 = tanh_pre(acc0[2]);                                                \
        float h3 = tanh_pre(acc0[3]);                                                \
        float h4 = tanh_pre(acc1[0]);                                                \
        float h5 = tanh_pre(acc1[1]);                                                \
        float h6 = tanh_pre(acc1[2]);                                                \
        float h7 = tanh_pre(acc1[3]);                                                \
        *(uint2*)((WB) + woff0) = make_uint2(cvt_pk_bf16(h0, h1),                    \
                                             cvt_pk_bf16(h2, h3));                   \
        *(uint2*)((WB) + woff1) = make_uint2(cvt_pk_bf16(h4, h5),                    \
                                             cvt_pk_bf16(h6, h7));                   \
        asm volatile("s_waitcnt lgkmcnt(0)" ::: "memory");                           \
        __builtin_amdgcn_s_barrier();                                                \
        px[0] = pk_add(px[0], f32x2{h0, h1});                                        \
        px[1] = pk_add(px[1], f32x2{h2, h3});                                        \
        px[2] = pk_add(px[2], f32x2{h4, h5});                                        \
        px[3] = pk_add(px[3], f32x2{h6, h7});                                        \
    }

        for (int i = 0; i < S_LEN - 4; i += 2) {
            STEP2(hb0, hb1, xc0, 1)
            STEP2(hb1, hb0, xc1, 1)
        }
        STEP2(hb0, hb1, xc0, 1)
        STEP2(hb1, hb0, xc1, 1)
        STEP2(hb0, hb1, xc0, 0)
        STEP2(hb1, hb0, xc1, 0)
#undef STEP2

        int b = half * 16 + l15;
        #pragma unroll
        for (int rr = 0; rr < 4; rr++) {
            pooled[b * 512 + dir * 256 + t0 * 16 + kg * 4 + rr] = px[rr >> 1][rr & 1];
            pooled[b * 512 + dir * 256 + t1 * 16 + kg * 4 + rr] = px[2 + (rr >> 1)][rr & 1];
        }
    } else {
        // ---- single-chain wave: tile t = 4g+1+r ----
        int t = 4 * g + 1 + r;
        bf16x8 wf[8];
        #pragma unroll
        for (int kb = 0; kb < 8; kb++) {
            int jb = ((dir * 8 + kb) * 4 + kg) * 256;
            wf[kb] = *(const bf16x8*)(Whp + (size_t)(jb + t * 16 + l15) * 8);
        }
        int woff = WOFF(t);
        int xoff = s0 * 32768 + xrec + (r + 1) * 8;   // quarter r+1 (8B)
        uint2 xc0 = *(const uint2*)(xqb + xoff); xoff += sdelta;
        uint2 xc1 = *(const uint2*)(xqb + xoff); xoff += sdelta;
        f32x2 px[2] = {};

#define STEP1(RB, WB, XC, DO_PF)                                                     \
    {                                                                                \
        const char* rb = (RB) + rbase;                                               \
        bf16x8 hf[8];                                                                \
        _Pragma("unroll")                                                            \
        for (int kb = 0; kb < 8; kb++)                                               \
            hf[kb] = *(const bf16x8*)(rb + kb * 1024);                               \
        f32x4 acc;                                                                   \
        acc[0] = bflo(XC.x);                                                         \
        acc[1] = bfhi(XC.x);                                                         \
        acc[2] = bflo(XC.y);                                                         \
        acc[3] = bfhi(XC.y);                                                         \
        if (DO_PF) { XC = *(const uint2*)(xqb + xoff); xoff += sdelta; }             \
        _Pragma("unroll")                                                            \
        for (int kb = 0; kb < 8; kb++)                                               \
            acc = __builtin_amdgcn_mfma_f32_16x16x32_bf16(wf[kb], hf[kb],            \
                                                          acc, 0, 0, 0);             \
        float h0 = tanh_pre(acc[0]);                                                 \
        float h1 = tanh_pre(acc[1]);                                                 \
        float h2 = tanh_pre(acc[2]);                                                 \
        float h3 = tanh_pre(acc[3]);                                                 \
        *(uint2*)((WB) + woff) = make_uint2(cvt_pk_bf16(h0, h1),                     \
                                            cvt_pk_bf16(h2, h3));                    \
        asm volatile("s_waitcnt lgkmcnt(0)" ::: "memory");                           \
        __builtin_amdgcn_s_barrier();                                                \
        px[0] = pk_add(px[0], f32x2{h0, h1});                                        \
        px[1] = pk_add(px[1], f32x2{h2, h3});                                        \
    }

        for (int i = 0; i < S_LEN - 4; i += 2) {
            STEP1(hb0, hb1, xc0, 1)
            STEP1(hb1, hb0, xc1, 1)
        }
        STEP1(hb0, hb1, xc0, 1)
        STEP1(hb1, hb0, xc1, 1)
        STEP1(hb0, hb1, xc0, 0)
        STEP1(hb1, hb0, xc1, 0)
#undef STEP1

        int b = half * 16 + l15;
        #pragma unroll
        for (int rr = 0; rr < 4; rr++)
            pooled[b * 512 + dir * 256 + t * 16 + kg * 4 + rr] = px[rr >> 1][rr & 1];
    }
#undef WOFF
}

// ---------- K4: head: tanh(mean) @ fc_W^T + fc_b ----------
__global__ __launch_bounds__(64) void k_head(
    const float* __restrict__ pooled, const float* __restrict__ fcW,
    const float* __restrict__ fcb, float* __restrict__ out)
{
    int b = blockIdx.x;
    int lane = threadIdx.x;
    float p[GG] = {0, 0, 0, 0, 0};
    for (int jj = lane; jj < 512; jj += 64) {
        float a = tanhf_fast(pooled[b * 512 + jj] * (1.0f / 2048.0f));
        #pragma unroll
        for (int g = 0; g < GG; g++) p[g] += a * fcW[g * 512 + jj];
    }
    #pragma unroll
    for (int g = 0; g < GG; g++)
        #pragma unroll
        for (int off = 32; off; off >>= 1) p[g] += __shfl_xor(p[g], off);
    if (lane == 0) {
        #pragma unroll
        for (int g = 0; g < GG; g++) out[b * GG + g] = p[g] + fcb[g];
    }
}

// ---------- launcher ----------
extern "C" void kernel_launch(void* const* d_in, const int* in_sizes, int n_in,
                              void* d_out, int out_size, void* d_ws, size_t ws_size,
                              hipStream_t stream)
{
    const int* tok = (const int*)d_in[0];
    const float* emb = (const float*)d_in[1];
    const float* Wih_f = (const float*)d_in[2];
    const float* Whh_f = (const float*)d_in[3];
    const float* bih_f = (const float*)d_in[4];
    const float* bhh_f = (const float*)d_in[5];
    const float* Wih_b = (const float*)d_in[6];
    const float* Whh_b = (const float*)d_in[7];
    const float* bih_b = (const float*)d_in[8];
    const float* bhh_b = (const float*)d_in[9];
    const float* fcW = (const float*)d_in[10];
    const float* fcb = (const float*)d_in[11];
    float* out = (float*)d_out;

    char* ws = (char*)d_ws;
    unsigned short* xq   = (unsigned short*)(ws);                       // 67,108,864 B
    unsigned short* Wp   = (unsigned short*)(ws + 67108864);            //    327,680 B
    unsigned short* Whp  = (unsigned short*)(ws + 67108864 + 327680);   //    262,144 B
    float* biasc         = (float*)(ws + 67108864 + 327680 + 262144);   //      2,048 B
    float* pooled        = (float*)(ws + 67108864 + 327680 + 262144 + 2048); // 65,536 B

    hipLaunchKernelGGL(k_pack, dim3(1154), dim3(256), 0, stream,
                       Wih_f, Whh_f, bih_f, bhh_f, Wih_b, Whh_b, bih_b, bhh_b,
                       Wp, Whp, biasc);
    hipLaunchKernelGGL(k_xproj, dim3(2048), dim3(1024), 0, stream,
                       tok, emb, Wp, biasc, xq);
    hipLaunchKernelGGL(k_rnn, dim3(4), dim3(768), 0, stream, xq, Whp, pooled);
    hipLaunchKernelGGL(k_head, dim3(32), dim3(64), 0, stream, pooled, fcW, fcb, out);
}